// Round 7
// baseline (93.285 us; speedup 1.0000x reference)
//
#include <hip/hip_runtime.h>
#include <hip/hip_bf16.h>

#define N_NODES 8192
#define DIN     256
#define DOUT    128
#define NHEAD   2
#define CTOT    256          // NHEAD*DOUT, flat channel dim
#define NWORDS  256          // N_NODES/32 bitmask words per row
#define LRELU_A 0.2f
#define CAP     512          // max supported degree (actual max ~66)

typedef __attribute__((ext_vector_type(8))) short bf16x8;   // MFMA A/B frag (4 VGPR)
typedef __attribute__((ext_vector_type(4))) float f32x4;    // MFMA C/D frag

// bf16 helpers
__device__ __forceinline__ float bf(unsigned short u) {
    return __uint_as_float((unsigned)u << 16);
}
__device__ __forceinline__ unsigned short f2bf(float f) {
    unsigned u = __float_as_uint(f);
    u = (u + 0x7fffu + ((u >> 16) & 1u)) >> 16;
    return (unsigned short)u;
}
__device__ __forceinline__ unsigned pk(float a, float b) {
    return (unsigned)f2bf(a) | ((unsigned)f2bf(b) << 16);
}

// ---------------- fast zero of adj bitmask + S_all ---------------------------
__global__ __launch_bounds__(256) void k_clear(float4* __restrict__ adjp,
                                               float4* __restrict__ sallp) {
    const float4 z = make_float4(0.f, 0.f, 0.f, 0.f);
    int b = blockIdx.x, t = threadIdx.x;
    if (b < 2048) {
        adjp[b * 256 + t] = z;
    } else if (t < 64) {
        sallp[t] = z;
    }
}

// ---------------- adjacency bitmask build (dedup via atomicOr) ----------------
__global__ __launch_bounds__(256) void k_build_adj(const int* __restrict__ ei, int E,
                                                   unsigned int* __restrict__ adjw) {
    int e = blockIdx.x * blockDim.x + threadIdx.x;
    if (e < E) {
        int src = ei[e];
        int dst = ei[E + e];
        atomicOr(&adjw[(size_t)src * NWORDS + (dst >> 5)], 1u << (dst & 31));
    }
}

// ---------------- MFMA bf16 GEMM: hb16[n][c] = bf16(sum_f x[n][f]*W[c][f]) ---
// Block tile 128(M) x 64(N), K-step 32, grid 64x4 = 256 blocks (1/CU).
// LDS tiles row-stride 40 ushorts (80B = 5x16B -> ds_read_b128 conflict-free).
// Frag layout (gfx950, m89/m91-verified): A/B lane: row=lane&15, k-octet=lane>>4;
// C/D lane: col=lane&15, row=(lane>>4)*4+reg.
#define LDR 40
__global__ __launch_bounds__(256) void k_gemm(const float* __restrict__ x,
                                              const float* __restrict__ W,
                                              unsigned short* __restrict__ hb16) {
    __shared__ unsigned short As[128 * LDR];  // 10 KB
    __shared__ unsigned short Bs[64 * LDR];   //  5 KB
    int t = threadIdx.x, wv = t >> 6, lane = t & 63;
    int bm = blockIdx.x * 128;
    int bn = blockIdx.y * 64;
    int fr = lane & 15, ksl = lane >> 4;

    f32x4 acc[2][4] = {};

    for (int k0 = 0; k0 < DIN; k0 += 32) {
        // stage A: 512 (row,slot) 16B-chunks; 2 per thread
        #pragma unroll
        for (int i = 0; i < 2; ++i) {
            int idx = i * 256 + t;
            int row = idx >> 2, slot = idx & 3;
            const float4* src = reinterpret_cast<const float4*>(&x[(bm + row) * DIN + k0 + slot * 8]);
            float4 v0 = src[0], v1 = src[1];
            uint4 q = make_uint4(pk(v0.x, v0.y), pk(v0.z, v0.w), pk(v1.x, v1.y), pk(v1.z, v1.w));
            *reinterpret_cast<uint4*>(&As[row * LDR + slot * 8]) = q;
        }
        // stage B: 256 chunks; 1 per thread
        {
            int row = t >> 2, slot = t & 3;
            const float4* src = reinterpret_cast<const float4*>(&W[(bn + row) * DIN + k0 + slot * 8]);
            float4 v0 = src[0], v1 = src[1];
            uint4 q = make_uint4(pk(v0.x, v0.y), pk(v0.z, v0.w), pk(v1.x, v1.y), pk(v1.z, v1.w));
            *reinterpret_cast<uint4*>(&Bs[row * LDR + slot * 8]) = q;
        }
        __syncthreads();

        bf16x8 af[2], bfr[4];
        #pragma unroll
        for (int fm = 0; fm < 2; ++fm)
            af[fm] = *reinterpret_cast<const bf16x8*>(&As[(wv * 32 + fm * 16 + fr) * LDR + ksl * 8]);
        #pragma unroll
        for (int fn = 0; fn < 4; ++fn)
            bfr[fn] = *reinterpret_cast<const bf16x8*>(&Bs[(fn * 16 + fr) * LDR + ksl * 8]);
        #pragma unroll
        for (int fm = 0; fm < 2; ++fm)
            #pragma unroll
            for (int fn = 0; fn < 4; ++fn)
                acc[fm][fn] = __builtin_amdgcn_mfma_f32_16x16x32_bf16(af[fm], bfr[fn], acc[fm][fn], 0, 0, 0);
        __syncthreads();
    }

    // epilogue: C/D col=lane&15, row=(lane>>4)*4+r
    #pragma unroll
    for (int fm = 0; fm < 2; ++fm) {
        int r0 = bm + wv * 32 + fm * 16 + ksl * 4;
        #pragma unroll
        for (int fn = 0; fn < 4; ++fn) {
            int c = bn + fn * 16 + fr;
            #pragma unroll
            for (int r = 0; r < 4; ++r)
                hb16[(size_t)(r0 + r) * CTOT + c] = f2bf(acc[fm][fn][r]);
        }
    }
}

// ---------------- fused scores + column sum (single hb16 pass) ---------------
// 256 blocks x 32 rows. Lane owns channels lane*4..+3; head = lane>>5.
__global__ __launch_bounds__(256) void k_sc2(const uint2* __restrict__ hb16v,
                                             const float* __restrict__ a,
                                             float* __restrict__ s_src,
                                             float* __restrict__ s_dst,
                                             float* __restrict__ S_all) {
    __shared__ float4 cpart[4][64];
    int t = threadIdx.x, wv = t >> 6, lane = t & 63;
    int head = lane >> 5;
    int cb = (lane & 31) * 4;
    const float4 as4 = *reinterpret_cast<const float4*>(&a[head * 256 + cb]);
    const float4 ad4 = *reinterpret_cast<const float4*>(&a[head * 256 + 128 + cb]);
    int r0 = blockIdx.x * 32 + wv * 8;
    float4 cs = make_float4(0.f, 0.f, 0.f, 0.f);
    for (int r = r0; r < r0 + 8; ++r) {
        uint2 hv = hb16v[r * 64 + lane];
        float f0 = bf((unsigned short)hv.x), f1 = bf((unsigned short)(hv.x >> 16));
        float f2 = bf((unsigned short)hv.y), f3 = bf((unsigned short)(hv.y >> 16));
        cs.x += f0; cs.y += f1; cs.z += f2; cs.w += f3;
        float ps = f0 * as4.x + f1 * as4.y + f2 * as4.z + f3 * as4.w;
        float pd = f0 * ad4.x + f1 * ad4.y + f2 * ad4.z + f3 * ad4.w;
        #pragma unroll
        for (int off = 16; off; off >>= 1) {
            ps += __shfl_xor(ps, off);
            pd += __shfl_xor(pd, off);
        }
        if ((lane & 31) == 0) {
            s_src[head * N_NODES + r] = ps;
            s_dst[head * N_NODES + r] = pd;
        }
    }
    cpart[wv][lane] = cs;
    __syncthreads();
    if (t < 64) {
        float4 c0 = cpart[0][t], c1 = cpart[1][t], c2 = cpart[2][t], c3 = cpart[3][t];
        atomicAdd(&S_all[t * 4 + 0], c0.x + c1.x + c2.x + c3.x);
        atomicAdd(&S_all[t * 4 + 1], c0.y + c1.y + c2.y + c3.y);
        atomicAdd(&S_all[t * 4 + 2], c0.z + c1.z + c2.z + c3.z);
        atomicAdd(&S_all[t * 4 + 3], c0.w + c1.w + c2.w + c3.w);
    }
}

// ---------------- attention row kernel (unchanged from R6) -------------------
__global__ __launch_bounds__(256) void k_attn(const unsigned int* __restrict__ adjw,
                                              const float* __restrict__ s_src,
                                              const float* __restrict__ s_dst,
                                              const unsigned short* __restrict__ hb16,
                                              const float* __restrict__ S_all,
                                              float* __restrict__ out) {
    __shared__ unsigned short nbr[CAP];
    __shared__ float          ew0[CAP];
    __shared__ float          ew1[CAP];
    __shared__ int            wtot[4];
    __shared__ float          zr0[4];
    __shared__ float          zr1[4];

    int i    = blockIdx.x;
    int t    = threadIdx.x;
    int lane = t & 63;
    int wv   = t >> 6;

    unsigned int w = adjw[(size_t)i * NWORDS + t];
    int cnt = __popc(w);
    int inc = cnt;
    #pragma unroll
    for (int off = 1; off < 64; off <<= 1) {
        int v = __shfl_up(inc, off);
        if (lane >= off) inc += v;
    }
    if (lane == 63) wtot[wv] = inc;
    __syncthreads();
    int base = 0;
    #pragma unroll
    for (int q = 0; q < 3; ++q) if (q < wv) base += wtot[q];
    int deg = wtot[0] + wtot[1] + wtot[2] + wtot[3];
    int pos = base + inc - cnt;
    unsigned int ww = w;
    while (ww) {
        int b = __ffs(ww) - 1;
        ww &= ww - 1;
        if (pos < CAP) nbr[pos] = (unsigned short)(t * 32 + b);
        ++pos;
    }
    if (deg > CAP) deg = CAP;
    __syncthreads();

    float ss0 = s_src[i], ss1 = s_src[N_NODES + i];
    float z0 = 0.f, z1 = 0.f;
    for (int k = t; k < deg; k += 256) {
        int j = nbr[k];
        float v0 = ss0 + s_dst[j];
        float v1 = ss1 + s_dst[N_NODES + j];
        float e0 = v0 > 0.f ? v0 : LRELU_A * v0;
        float e1 = v1 > 0.f ? v1 : LRELU_A * v1;
        float w0 = expf(e0) - 1.f;
        float w1 = expf(e1) - 1.f;
        ew0[k] = w0; ew1[k] = w1;
        z0 += w0; z1 += w1;
    }
    #pragma unroll
    for (int off = 32; off; off >>= 1) {
        z0 += __shfl_xor(z0, off);
        z1 += __shfl_xor(z1, off);
    }
    if (lane == 0) { zr0[wv] = z0; zr1[wv] = z1; }
    __syncthreads();
    float Z0 = (float)N_NODES + zr0[0] + zr0[1] + zr0[2] + zr0[3];
    float Z1 = (float)N_NODES + zr1[0] + zr1[1] + zr1[2] + zr1[3];

    int hh = t >> 7;
    const float* ewh = hh ? ew1 : ew0;
    float Zh = hh ? Z1 : Z0;
    float acc = 0.f;
    int k = 0;
    for (; k + 4 <= deg; k += 4) {
        int j0 = nbr[k], j1 = nbr[k + 1], j2 = nbr[k + 2], j3 = nbr[k + 3];
        float w0 = ewh[k], w1 = ewh[k + 1], w2 = ewh[k + 2], w3 = ewh[k + 3];
        float v0 = bf(hb16[j0 * CTOT + t]);
        float v1 = bf(hb16[j1 * CTOT + t]);
        float v2 = bf(hb16[j2 * CTOT + t]);
        float v3 = bf(hb16[j3 * CTOT + t]);
        acc = fmaf(w0, v0, acc);
        acc = fmaf(w1, v1, acc);
        acc = fmaf(w2, v2, acc);
        acc = fmaf(w3, v3, acc);
    }
    for (; k < deg; ++k)
        acc = fmaf(ewh[k], bf(hb16[nbr[k] * CTOT + t]), acc);

    float o = (S_all[t] + acc) / Zh;
    o = o > 0.f ? o : expm1f(o);           // ELU (alpha=1)
    out[i * CTOT + t] = o;
}

// ---------------- launch ------------------------------------------------------
extern "C" void kernel_launch(void* const* d_in, const int* in_sizes, int n_in,
                              void* d_out, int out_size, void* d_ws, size_t ws_size,
                              hipStream_t stream) {
    const float* x  = (const float*)d_in[0];
    const float* W  = (const float*)d_in[1];
    const float* a  = (const float*)d_in[2];
    const int*   ei = (const int*)d_in[3];
    int E = in_sizes[3] / 2;
    float* out = (float*)d_out;

    char* ws = (char*)d_ws;
    size_t off = 0;
    auto alloc = [&](size_t bytes) { char* p = ws + off; off += (bytes + 255) & ~(size_t)255; return p; };
    unsigned int*   adjw  = (unsigned int*)  alloc((size_t)N_NODES * NWORDS * 4); // 8 MB
    float*          S_all = (float*)         alloc(CTOT * 4);
    float*          s_src = (float*)         alloc((size_t)NHEAD * N_NODES * 4);
    float*          s_dst = (float*)         alloc((size_t)NHEAD * N_NODES * 4);
    unsigned short* hb16  = (unsigned short*)alloc((size_t)N_NODES * CTOT * 2);  // 4 MB

    k_clear<<<2049, 256, 0, stream>>>((float4*)adjw, (float4*)S_all);
    k_build_adj<<<(E + 255) / 256, 256, 0, stream>>>(ei, E, adjw);
    k_gemm<<<dim3(64, 4), 256, 0, stream>>>(x, W, hb16);
    k_sc2<<<256, 256, 0, stream>>>((const uint2*)hb16, a, s_src, s_dst, S_all);
    k_attn<<<N_NODES, 256, 0, stream>>>(adjw, s_src, s_dst, hb16, S_all, out);
}

// Round 8
// 82.644 us; speedup vs baseline: 1.1288x; 1.1288x over previous
//
#include <hip/hip_runtime.h>
#include <hip/hip_bf16.h>

#define N_NODES 8192
#define DIN     256
#define DOUT    128
#define NHEAD   2
#define CTOT    256          // NHEAD*DOUT, flat channel dim
#define NWORDS  256          // N_NODES/32 bitmask words per row
#define LRELU_A 0.2f
#define CAP     512          // max supported degree (actual max ~66)

typedef __attribute__((ext_vector_type(8))) short bf16x8;   // MFMA A/B frag (4 VGPR)
typedef __attribute__((ext_vector_type(4))) float f32x4;    // MFMA C/D frag

// bf16 helpers
__device__ __forceinline__ float bf(unsigned short u) {
    return __uint_as_float((unsigned)u << 16);
}
__device__ __forceinline__ unsigned short f2bf(float f) {
    unsigned u = __float_as_uint(f);
    u = (u + 0x7fffu + ((u >> 16) & 1u)) >> 16;
    return (unsigned short)u;
}
__device__ __forceinline__ unsigned pk(float a, float b) {
    return (unsigned)f2bf(a) | ((unsigned)f2bf(b) << 16);
}

// =============================================================================
// K1: blocks [0,2048) clear adj bitmask; block 2048 clears S_all;
//     blocks [2049, 2305) run the MFMA bf16 GEMM (tile 128x64, K-step 32).
// LDS row-stride 40 ushorts (80B = 5x16B -> ds_read_b128 bank-conflict-free).
// Frag layout (gfx950, m89/m91-verified): A/B lane: row=lane&15, k-oct=lane>>4;
// C/D lane: col=lane&15, row=(lane>>4)*4+reg.
// =============================================================================
#define LDR 40
__global__ __launch_bounds__(256) void k_pre(const float* __restrict__ x,
                                             const float* __restrict__ W,
                                             unsigned short* __restrict__ hb16,
                                             float4* __restrict__ adjp,
                                             float4* __restrict__ sallp) {
    __shared__ unsigned short As[128 * LDR];  // 10 KB
    __shared__ unsigned short Bs[64 * LDR];   //  5 KB
    int b = blockIdx.x, t = threadIdx.x;

    if (b < 2048) {                       // clear 8 MB bitmask
        adjp[b * 256 + t] = make_float4(0.f, 0.f, 0.f, 0.f);
        return;
    }
    if (b == 2048) {                      // clear S_all (256 floats)
        if (t < 64) sallp[t] = make_float4(0.f, 0.f, 0.f, 0.f);
        return;
    }

    int g  = b - 2049;                    // 0..255 GEMM tiles
    int bm = (g & 63) * 128;
    int bn = (g >> 6) * 64;
    int wv = t >> 6, lane = t & 63;
    int fr = lane & 15, ksl = lane >> 4;

    f32x4 acc[2][4] = {};

    for (int k0 = 0; k0 < DIN; k0 += 32) {
        #pragma unroll
        for (int i = 0; i < 2; ++i) {
            int idx = i * 256 + t;
            int row = idx >> 2, slot = idx & 3;
            const float4* src = reinterpret_cast<const float4*>(&x[(bm + row) * DIN + k0 + slot * 8]);
            float4 v0 = src[0], v1 = src[1];
            uint4 q = make_uint4(pk(v0.x, v0.y), pk(v0.z, v0.w), pk(v1.x, v1.y), pk(v1.z, v1.w));
            *reinterpret_cast<uint4*>(&As[row * LDR + slot * 8]) = q;
        }
        {
            int row = t >> 2, slot = t & 3;
            const float4* src = reinterpret_cast<const float4*>(&W[(bn + row) * DIN + k0 + slot * 8]);
            float4 v0 = src[0], v1 = src[1];
            uint4 q = make_uint4(pk(v0.x, v0.y), pk(v0.z, v0.w), pk(v1.x, v1.y), pk(v1.z, v1.w));
            *reinterpret_cast<uint4*>(&Bs[row * LDR + slot * 8]) = q;
        }
        __syncthreads();

        bf16x8 af[2], bfr[4];
        #pragma unroll
        for (int fm = 0; fm < 2; ++fm)
            af[fm] = *reinterpret_cast<const bf16x8*>(&As[(wv * 32 + fm * 16 + fr) * LDR + ksl * 8]);
        #pragma unroll
        for (int fn = 0; fn < 4; ++fn)
            bfr[fn] = *reinterpret_cast<const bf16x8*>(&Bs[(fn * 16 + fr) * LDR + ksl * 8]);
        #pragma unroll
        for (int fm = 0; fm < 2; ++fm)
            #pragma unroll
            for (int fn = 0; fn < 4; ++fn)
                acc[fm][fn] = __builtin_amdgcn_mfma_f32_16x16x32_bf16(af[fm], bfr[fn], acc[fm][fn], 0, 0, 0);
        __syncthreads();
    }

    #pragma unroll
    for (int fm = 0; fm < 2; ++fm) {
        int r0 = bm + wv * 32 + fm * 16 + ksl * 4;
        #pragma unroll
        for (int fn = 0; fn < 4; ++fn) {
            int c = bn + fn * 16 + fr;
            #pragma unroll
            for (int r = 0; r < 4; ++r)
                hb16[(size_t)(r0 + r) * CTOT + c] = f2bf(acc[fm][fn][r]);
        }
    }
}

// =============================================================================
// K2: blocks [0, nbBuild) scatter edges into bitmask (atomicOr dedup);
//     blocks [nbBuild, nbBuild+256) fused scores + column-sum over hb16.
// =============================================================================
__global__ __launch_bounds__(256) void k_mid(const int* __restrict__ ei, int E, int nbBuild,
                                             unsigned int* __restrict__ adjw,
                                             const uint2* __restrict__ hb16v,
                                             const float* __restrict__ a,
                                             float* __restrict__ s_src,
                                             float* __restrict__ s_dst,
                                             float* __restrict__ S_all) {
    __shared__ float4 cpart[4][64];
    int b = blockIdx.x, t = threadIdx.x;

    if (b < nbBuild) {                    // edge scatter
        int e = b * 256 + t;
        if (e < E) {
            int src = ei[e];
            int dst = ei[E + e];
            atomicOr(&adjw[(size_t)src * NWORDS + (dst >> 5)], 1u << (dst & 31));
        }
        return;
    }

    int blk = b - nbBuild;                // 0..255: scores + colsum
    int wv = t >> 6, lane = t & 63;
    int head = lane >> 5;
    int cb = (lane & 31) * 4;
    const float4 as4 = *reinterpret_cast<const float4*>(&a[head * 256 + cb]);
    const float4 ad4 = *reinterpret_cast<const float4*>(&a[head * 256 + 128 + cb]);
    int r0 = blk * 32 + wv * 8;
    float4 cs = make_float4(0.f, 0.f, 0.f, 0.f);
    for (int r = r0; r < r0 + 8; ++r) {
        uint2 hv = hb16v[r * 64 + lane];
        float f0 = bf((unsigned short)hv.x), f1 = bf((unsigned short)(hv.x >> 16));
        float f2 = bf((unsigned short)hv.y), f3 = bf((unsigned short)(hv.y >> 16));
        cs.x += f0; cs.y += f1; cs.z += f2; cs.w += f3;
        float ps = f0 * as4.x + f1 * as4.y + f2 * as4.z + f3 * as4.w;
        float pd = f0 * ad4.x + f1 * ad4.y + f2 * ad4.z + f3 * ad4.w;
        #pragma unroll
        for (int off = 16; off; off >>= 1) {
            ps += __shfl_xor(ps, off);
            pd += __shfl_xor(pd, off);
        }
        if ((lane & 31) == 0) {
            s_src[head * N_NODES + r] = ps;
            s_dst[head * N_NODES + r] = pd;
        }
    }
    cpart[wv][lane] = cs;
    __syncthreads();
    if (t < 64) {
        float4 c0 = cpart[0][t], c1 = cpart[1][t], c2 = cpart[2][t], c3 = cpart[3][t];
        atomicAdd(&S_all[t * 4 + 0], c0.x + c1.x + c2.x + c3.x);
        atomicAdd(&S_all[t * 4 + 1], c0.y + c1.y + c2.y + c3.y);
        atomicAdd(&S_all[t * 4 + 2], c0.z + c1.z + c2.z + c3.z);
        atomicAdd(&S_all[t * 4 + 3], c0.w + c1.w + c2.w + c3.w);
    }
}

// =============================================================================
// K3: attention row kernel — block per row, thread t owns channel t,
// in-LDS compaction + weights, 8-deep ILP bf16 gather.
// w = exp(leakyrelu(s_i+s_j)) - 1 (max-shift skipped: scores bounded, fp32-safe),
// Z = N + sum(w), out = elu((S_all + sum w*h_j)/Z).
// =============================================================================
__global__ __launch_bounds__(256) void k_attn(const unsigned int* __restrict__ adjw,
                                              const float* __restrict__ s_src,
                                              const float* __restrict__ s_dst,
                                              const unsigned short* __restrict__ hb16,
                                              const float* __restrict__ S_all,
                                              float* __restrict__ out) {
    __shared__ unsigned short nbr[CAP];
    __shared__ float          ew0[CAP];
    __shared__ float          ew1[CAP];
    __shared__ int            wtot[4];
    __shared__ float          zr0[4];
    __shared__ float          zr1[4];

    int i    = blockIdx.x;
    int t    = threadIdx.x;
    int lane = t & 63;
    int wv   = t >> 6;

    unsigned int w = adjw[(size_t)i * NWORDS + t];
    int cnt = __popc(w);
    int inc = cnt;
    #pragma unroll
    for (int off = 1; off < 64; off <<= 1) {
        int v = __shfl_up(inc, off);
        if (lane >= off) inc += v;
    }
    if (lane == 63) wtot[wv] = inc;
    __syncthreads();
    int base = 0;
    #pragma unroll
    for (int q = 0; q < 3; ++q) if (q < wv) base += wtot[q];
    int deg = wtot[0] + wtot[1] + wtot[2] + wtot[3];
    int pos = base + inc - cnt;
    unsigned int ww = w;
    while (ww) {
        int b = __ffs(ww) - 1;
        ww &= ww - 1;
        if (pos < CAP) nbr[pos] = (unsigned short)(t * 32 + b);
        ++pos;
    }
    if (deg > CAP) deg = CAP;
    __syncthreads();

    float ss0 = s_src[i], ss1 = s_src[N_NODES + i];
    float z0 = 0.f, z1 = 0.f;
    for (int k = t; k < deg; k += 256) {
        int j = nbr[k];
        float v0 = ss0 + s_dst[j];
        float v1 = ss1 + s_dst[N_NODES + j];
        float e0 = v0 > 0.f ? v0 : LRELU_A * v0;
        float e1 = v1 > 0.f ? v1 : LRELU_A * v1;
        float w0 = expf(e0) - 1.f;
        float w1 = expf(e1) - 1.f;
        ew0[k] = w0; ew1[k] = w1;
        z0 += w0; z1 += w1;
    }
    #pragma unroll
    for (int off = 32; off; off >>= 1) {
        z0 += __shfl_xor(z0, off);
        z1 += __shfl_xor(z1, off);
    }
    if (lane == 0) { zr0[wv] = z0; zr1[wv] = z1; }
    __syncthreads();
    float Z0 = (float)N_NODES + zr0[0] + zr0[1] + zr0[2] + zr0[3];
    float Z1 = (float)N_NODES + zr1[0] + zr1[1] + zr1[2] + zr1[3];

    // gather: 8-deep ILP on L2-resident 2B loads
    int hh = t >> 7;
    const float* ewh = hh ? ew1 : ew0;
    float Zh = hh ? Z1 : Z0;
    float acc = 0.f;
    int k = 0;
    for (; k + 8 <= deg; k += 8) {
        int j0 = nbr[k+0], j1 = nbr[k+1], j2 = nbr[k+2], j3 = nbr[k+3];
        int j4 = nbr[k+4], j5 = nbr[k+5], j6 = nbr[k+6], j7 = nbr[k+7];
        float w0 = ewh[k+0], w1 = ewh[k+1], w2 = ewh[k+2], w3 = ewh[k+3];
        float w4 = ewh[k+4], w5 = ewh[k+5], w6 = ewh[k+6], w7 = ewh[k+7];
        float v0 = bf(hb16[j0 * CTOT + t]);
        float v1 = bf(hb16[j1 * CTOT + t]);
        float v2 = bf(hb16[j2 * CTOT + t]);
        float v3 = bf(hb16[j3 * CTOT + t]);
        float v4 = bf(hb16[j4 * CTOT + t]);
        float v5 = bf(hb16[j5 * CTOT + t]);
        float v6 = bf(hb16[j6 * CTOT + t]);
        float v7 = bf(hb16[j7 * CTOT + t]);
        acc = fmaf(w0, v0, acc); acc = fmaf(w1, v1, acc);
        acc = fmaf(w2, v2, acc); acc = fmaf(w3, v3, acc);
        acc = fmaf(w4, v4, acc); acc = fmaf(w5, v5, acc);
        acc = fmaf(w6, v6, acc); acc = fmaf(w7, v7, acc);
    }
    for (; k + 4 <= deg; k += 4) {
        int j0 = nbr[k], j1 = nbr[k+1], j2 = nbr[k+2], j3 = nbr[k+3];
        float w0 = ewh[k], w1 = ewh[k+1], w2 = ewh[k+2], w3 = ewh[k+3];
        float v0 = bf(hb16[j0 * CTOT + t]);
        float v1 = bf(hb16[j1 * CTOT + t]);
        float v2 = bf(hb16[j2 * CTOT + t]);
        float v3 = bf(hb16[j3 * CTOT + t]);
        acc = fmaf(w0, v0, acc); acc = fmaf(w1, v1, acc);
        acc = fmaf(w2, v2, acc); acc = fmaf(w3, v3, acc);
    }
    for (; k < deg; ++k)
        acc = fmaf(ewh[k], bf(hb16[nbr[k] * CTOT + t]), acc);

    float o = (S_all[t] + acc) / Zh;
    o = o > 0.f ? o : expm1f(o);           // ELU (alpha=1)
    out[i * CTOT + t] = o;
}

// ---------------- launch ------------------------------------------------------
extern "C" void kernel_launch(void* const* d_in, const int* in_sizes, int n_in,
                              void* d_out, int out_size, void* d_ws, size_t ws_size,
                              hipStream_t stream) {
    const float* x  = (const float*)d_in[0];
    const float* W  = (const float*)d_in[1];
    const float* a  = (const float*)d_in[2];
    const int*   ei = (const int*)d_in[3];
    int E = in_sizes[3] / 2;
    float* out = (float*)d_out;

    char* ws = (char*)d_ws;
    size_t off = 0;
    auto alloc = [&](size_t bytes) { char* p = ws + off; off += (bytes + 255) & ~(size_t)255; return p; };
    unsigned int*   adjw  = (unsigned int*)  alloc((size_t)N_NODES * NWORDS * 4); // 8 MB
    float*          S_all = (float*)         alloc(CTOT * 4);
    float*          s_src = (float*)         alloc((size_t)NHEAD * N_NODES * 4);
    float*          s_dst = (float*)         alloc((size_t)NHEAD * N_NODES * 4);
    unsigned short* hb16  = (unsigned short*)alloc((size_t)N_NODES * CTOT * 2);  // 4 MB

    int nbBuild = (E + 255) / 256;
    k_pre<<<2305, 256, 0, stream>>>(x, W, hb16, (float4*)adjw, (float4*)S_all);
    k_mid<<<nbBuild + 256, 256, 0, stream>>>(ei, E, nbBuild, adjw,
                                             (const uint2*)hb16, a, s_src, s_dst, S_all);
    k_attn<<<N_NODES, 256, 0, stream>>>(adjw, s_src, s_dst, hb16, S_all, out);
}